// Round 1
// baseline (661.325 us; speedup 1.0000x reference)
//
#include <hip/hip_runtime.h>
#include <hip/hip_bf16.h>

// ---- problem constants (fixed by setup_inputs) ----
#define B_    4
#define LIN   13294
#define M_    (B_*LIN)     // 53176
#define D_    256
#define NH_   8
#define NL_   4
#define NP_   4
#define DFF_  1024

typedef __bf16 bf16;
typedef __attribute__((ext_vector_type(8))) __bf16 bfrag8;
typedef __attribute__((ext_vector_type(4))) __bf16 bf16x4;
typedef __attribute__((ext_vector_type(4))) float facc4;

// ---------------- elementwise: q = src + pos (fp32 + bf16) ----------------
__global__ __launch_bounds__(256) void make_q(const float* __restrict__ src,
                                              const float* __restrict__ pos,
                                              float* __restrict__ q,
                                              bf16* __restrict__ qb, int n4) {
  int i = blockIdx.x * 256 + threadIdx.x;
  if (i >= n4) return;
  float4 s = ((const float4*)src)[i];
  float4 p = ((const float4*)pos)[i];
  float4 v = {s.x + p.x, s.y + p.y, s.z + p.z, s.w + p.w};
  ((float4*)q)[i] = v;
  bf16 t4[4] = {(bf16)v.x, (bf16)v.y, (bf16)v.z, (bf16)v.w};
  ((uint2*)qb)[i] = *(uint2*)t4;
}

// ---------------- weight prep: transpose + bf16 convert ----------------
// Wt[n*K + k] = bf16(W[k*N + n]); packs offs_w/attn_w into one [384,256]
__global__ __launch_bounds__(256) void prep_weights(
    const float* __restrict__ vw, const float* __restrict__ ow,
    const float* __restrict__ aw, const float* __restrict__ outw,
    const float* __restrict__ f1w, const float* __restrict__ f2w,
    const float* __restrict__ ob, const float* __restrict__ ab,
    bf16* __restrict__ vwt, bf16* __restrict__ oawt, bf16* __restrict__ outwt,
    bf16* __restrict__ f1wt, bf16* __restrict__ f2wt, float* __restrict__ oabias) {
  int seg = blockIdx.y;
  int idx = blockIdx.x * 256 + threadIdx.x;
  if (seg == 6) {
    if (idx < 256) oabias[idx] = ob[idx];
    else if (idx < 384) oabias[idx] = ab[idx - 256];
    return;
  }
  const float* W; bf16* Wt; int K, N;
  switch (seg) {
    case 0: W = vw;   Wt = vwt;          K = 256;  N = 256;  break;
    case 1: W = ow;   Wt = oawt;         K = 256;  N = 256;  break;
    case 2: W = aw;   Wt = oawt + 65536; K = 256;  N = 128;  break;
    case 3: W = outw; Wt = outwt;        K = 256;  N = 256;  break;
    case 4: W = f1w;  Wt = f1wt;         K = 256;  N = 1024; break;
    default: W = f2w; Wt = f2wt;         K = 1024; N = 256;  break;
  }
  if (idx < K * N) {
    int n = idx / K, k = idx - n * K;
    Wt[idx] = (bf16)W[k * N + n];
  }
}

// ---------------- bf16 MFMA GEMM: C[M,N] = A[M,K] @ Bt[N,K]^T + bias ----------------
// 64x64 tile, BK=64, 4 waves: wave w owns cols [16w,16w+16), 4 row-tiles.
// mfma_f32_16x16x32_bf16 layouts (HW-verified):
//   A frag: m=lane&15, k=(lane>>4)*8+j ; B frag: n=lane&15, k=(lane>>4)*8+j
//   C/D:    col=lane&15, row=(lane>>4)*4+reg
template<bool RELU>
__global__ __launch_bounds__(256) void gemm_kernel(
    const bf16* __restrict__ A, const bf16* __restrict__ Bt,
    const float* __restrict__ bias, bf16* __restrict__ C,
    int Mdim, int K, int N) {
  __shared__ __align__(16) bf16 As[64][72];   // +8 pad breaks 16-way bank conflict
  __shared__ __align__(16) bf16 Bs[64][72];
  int m0 = blockIdx.x * 64;
  int n0 = blockIdx.y * 64;
  int t = threadIdx.x;
  int wave = t >> 6, lane = t & 63;
  int ln = lane & 15, quad = lane >> 4;

  facc4 acc[4];
  facc4 z = {0.f, 0.f, 0.f, 0.f};
  for (int r = 0; r < 4; r++) acc[r] = z;

  for (int k0 = 0; k0 < K; k0 += 64) {
    __syncthreads();
    #pragma unroll
    for (int i = 0; i < 2; i++) {
      int idx = t + i * 256;           // 0..511
      int row = idx >> 3, kc = (idx & 7) * 8;
      int ag = min(m0 + row, Mdim - 1);
      *(uint4*)&As[row][kc] = *(const uint4*)&A[(size_t)ag * K + k0 + kc];
      *(uint4*)&Bs[row][kc] = *(const uint4*)&Bt[(size_t)(n0 + row) * K + k0 + kc];
    }
    __syncthreads();
    #pragma unroll
    for (int kk = 0; kk < 64; kk += 32) {
      bfrag8 bfr = *(const bfrag8*)&Bs[16 * wave + ln][kk + quad * 8];
      #pragma unroll
      for (int r = 0; r < 4; r++) {
        bfrag8 afr = *(const bfrag8*)&As[r * 16 + ln][kk + quad * 8];
        acc[r] = __builtin_amdgcn_mfma_f32_16x16x32_bf16(afr, bfr, acc[r], 0, 0, 0);
      }
    }
  }
  int col = n0 + wave * 16 + ln;
  float bv = bias[col];
  #pragma unroll
  for (int r = 0; r < 4; r++) {
    #pragma unroll
    for (int reg = 0; reg < 4; reg++) {
      int row = m0 + r * 16 + quad * 4 + reg;
      if (row < Mdim) {
        float v = acc[r][reg] + bv;
        if (RELU) v = fmaxf(v, 0.f);
        C[(size_t)row * N + col] = (bf16)v;
      }
    }
  }
}

// ---------------- MSDA sampling: one wave per (query m, head h) ----------------
// lane = p*4 + cg : p=0..15 sample point (l=p>>2, pt=p&3), cg = 8-channel group.
__global__ __launch_bounds__(256) void msda_sample(
    const bf16* __restrict__ value,   // [B*LIN, 256] bf16 (= [B,LIN,NH,32])
    const bf16* __restrict__ OA,      // [M, 384] : 0..255 offs, 256..383 attn logits
    const float* __restrict__ ref,    // [M, 4, 2]
    bf16* __restrict__ sampled) {     // [M, 256]
  int gw = (blockIdx.x * 256 + threadIdx.x) >> 6;
  int lane = threadIdx.x & 63;
  int m = gw >> 3, h = gw & 7;
  if (m >= M_) return;
  int b = m / LIN;
  int p = lane >> 2, cg = lane & 3;
  int l = p >> 2, pt = p & 3;
  int Wl = (l == 0) ? 100 : (l == 1) ? 50 : (l == 2) ? 25 : 13;
  int Hl = Wl;  // square levels
  int st = (l == 0) ? 0 : (l == 1) ? 10000 : (l == 2) ? 12500 : 13125;

  // softmax over 16 points of this head (each lane holds its own point's logit)
  float logit = (float)OA[(size_t)m * 384 + 256 + h * 16 + p];
  float mx = logit;
  #pragma unroll
  for (int msk = 4; msk < 64; msk <<= 1) mx = fmaxf(mx, __shfl_xor(mx, msk));
  float e = __expf(logit - mx);
  float se = e;
  #pragma unroll
  for (int msk = 4; msk < 64; msk <<= 1) se += __shfl_xor(se, msk);
  float w = e / se;

  float rx = ref[((size_t)m * 4 + l) * 2 + 0];
  float ry = ref[((size_t)m * 4 + l) * 2 + 1];
  float ox = (float)OA[(size_t)m * 384 + ((h * 4 + l) * 4 + pt) * 2 + 0];
  float oy = (float)OA[(size_t)m * 384 + ((h * 4 + l) * 4 + pt) * 2 + 1];
  // loc*W - 0.5 == rx*W + ox - 0.5  (normalizer is (W,H))
  float x = rx * (float)Wl + ox - 0.5f;
  float y = ry * (float)Hl + oy - 0.5f;
  float x0f = floorf(x), y0f = floorf(y);
  float dx = x - x0f, dy = y - y0f;
  int x0 = (int)x0f, y0 = (int)y0f;

  float acc[8];
  #pragma unroll
  for (int j = 0; j < 8; j++) acc[j] = 0.f;

  size_t vbase = ((size_t)(b * LIN + st)) * 256 + h * 32 + cg * 8;
  #pragma unroll
  for (int c = 0; c < 4; c++) {
    int cx = c & 1, cy = c >> 1;
    int xi = x0 + cx, yi = y0 + cy;
    bool valid = (xi >= 0) && (xi < Wl) && (yi >= 0) && (yi < Hl);
    int xc = min(max(xi, 0), Wl - 1);
    int yc = min(max(yi, 0), Hl - 1);
    float cw = (cx ? dx : 1.f - dx) * (cy ? dy : 1.f - dy);
    cw = valid ? cw : 0.f;
    bfrag8 vv = *(const bfrag8*)(value + vbase + (size_t)(yc * Wl + xc) * 256);
    #pragma unroll
    for (int j = 0; j < 8; j++) acc[j] += cw * (float)vv[j];
  }
  #pragma unroll
  for (int j = 0; j < 8; j++) acc[j] *= w;
  // reduce over the 16 points (lane bits 2..5)
  #pragma unroll
  for (int msk = 4; msk < 64; msk <<= 1) {
    #pragma unroll
    for (int j = 0; j < 8; j++) acc[j] += __shfl_xor(acc[j], msk);
  }
  if (p == 0) {
    bf16 o8[8];
    #pragma unroll
    for (int j = 0; j < 8; j++) o8[j] = (bf16)acc[j];
    *(uint4*)(sampled + (size_t)m * 256 + h * 32 + cg * 8) = *(uint4*)o8;
  }
}

// ---------------- LayerNorm over 256: y = LN(a + res)*g + b ----------------
__device__ inline float4 load4f(const float* p) { return *(const float4*)p; }
__device__ inline float4 load4f(const bf16* p) {
  bf16x4 v = *(const bf16x4*)p;
  float4 r = {(float)v[0], (float)v[1], (float)v[2], (float)v[3]};
  return r;
}
template<typename RT>
__global__ __launch_bounds__(256) void ln_kernel(
    const bf16* __restrict__ a, const RT* __restrict__ res,
    const float* __restrict__ g, const float* __restrict__ beta,
    float* __restrict__ out_f, bf16* __restrict__ out_b, int Mdim) {
  int wave = threadIdx.x >> 6, lane = threadIdx.x & 63;
  int row = blockIdx.x * 4 + wave;
  if (row >= Mdim) return;
  size_t base = (size_t)row * 256 + lane * 4;
  float4 av = load4f(a + base);
  float4 rv = load4f(res + base);
  float4 v = {av.x + rv.x, av.y + rv.y, av.z + rv.z, av.w + rv.w};
  float s = v.x + v.y + v.z + v.w;
  #pragma unroll
  for (int msk = 1; msk < 64; msk <<= 1) s += __shfl_xor(s, msk);
  float mean = s * (1.f / 256.f);
  float4 d = {v.x - mean, v.y - mean, v.z - mean, v.w - mean};
  float sq = d.x * d.x + d.y * d.y + d.z * d.z + d.w * d.w;
  #pragma unroll
  for (int msk = 1; msk < 64; msk <<= 1) sq += __shfl_xor(sq, msk);
  float inv = rsqrtf(sq * (1.f / 256.f) + 1e-5f);
  float4 gv = *(const float4*)(g + lane * 4);
  float4 bv = *(const float4*)(beta + lane * 4);
  float4 y = {d.x * inv * gv.x + bv.x, d.y * inv * gv.y + bv.y,
              d.z * inv * gv.z + bv.z, d.w * inv * gv.w + bv.w};
  if (out_f) *(float4*)(out_f + base) = y;
  if (out_b) {
    bf16 t4[4] = {(bf16)y.x, (bf16)y.y, (bf16)y.z, (bf16)y.w};
    *(uint2*)(out_b + base) = *(uint2*)t4;
  }
}

extern "C" void kernel_launch(void* const* d_in, const int* in_sizes, int n_in,
                              void* d_out, int out_size, void* d_ws, size_t ws_size,
                              hipStream_t stream) {
  const float* src     = (const float*)d_in[0];
  const float* pos     = (const float*)d_in[1];
  const float* refpts  = (const float*)d_in[2];
  // d_in[3] spatial_shapes, d_in[4] level_start_index: compile-time constants
  const float* value_w = (const float*)d_in[5];
  const float* value_b = (const float*)d_in[6];
  const float* offs_w  = (const float*)d_in[7];
  const float* offs_b  = (const float*)d_in[8];
  const float* attn_w  = (const float*)d_in[9];
  const float* attn_b  = (const float*)d_in[10];
  const float* out_w   = (const float*)d_in[11];
  const float* out_b   = (const float*)d_in[12];
  const float* ln1_g   = (const float*)d_in[13];
  const float* ln1_b   = (const float*)d_in[14];
  const float* ff1_w   = (const float*)d_in[15];
  const float* ff1_b   = (const float*)d_in[16];
  const float* ff2_w   = (const float*)d_in[17];
  const float* ff2_b   = (const float*)d_in[18];
  const float* ln2_g   = (const float*)d_in[19];
  const float* ln2_b   = (const float*)d_in[20];

  char* ws = (char*)d_ws;
  size_t off = 0;
  auto take = [&](size_t bytes) -> char* {
    char* pp = ws + off;
    off += (bytes + 255) & ~(size_t)255;
    return pp;
  };
  // ws layout (~233 MB): hb (ff1 out, M*1024 bf16) aliases region R whose
  // contents (qb/value/OA/sampled) are all dead before ff1 runs.
  float* q      = (float*)take((size_t)M_ * 256 * 4);
  size_t szQB   = (size_t)M_ * 256 * 2;
  size_t szOA   = (size_t)M_ * 384 * 2;
  char* R       = take(szQB * 3 + szOA);
  bf16* qb      = (bf16*)R;
  bf16* valueb  = (bf16*)(R + szQB);
  bf16* OA      = (bf16*)(R + 2 * szQB);
  bf16* sampled = (bf16*)(R + 2 * szQB + szOA);
  bf16* hb      = (bf16*)R;                      // alias
  bf16* tmp     = (bf16*)take(szQB);             // src2, then ff2 out
  bf16* x       = (bf16*)take(szQB);             // LN1 out (bf16)
  bf16* vwt     = (bf16*)take(65536 * 2);
  bf16* oawt    = (bf16*)take(98304 * 2);
  bf16* outwt   = (bf16*)take(65536 * 2);
  bf16* f1wt    = (bf16*)take(262144 * 2);
  bf16* f2wt    = (bf16*)take(262144 * 2);
  float* oabias = (float*)take(384 * 4);
  (void)ws_size; (void)in_sizes; (void)n_in; (void)out_size;

  int n4 = M_ * 256 / 4;
  make_q<<<dim3((n4 + 255) / 256), dim3(256), 0, stream>>>(src, pos, q, qb, n4);
  prep_weights<<<dim3(1024, 7), dim3(256), 0, stream>>>(
      value_w, offs_w, attn_w, out_w, ff1_w, ff2_w, offs_b, attn_b,
      vwt, oawt, outwt, f1wt, f2wt, oabias);

  dim3 blk(256);
  int mt = (M_ + 63) / 64;  // 831
  gemm_kernel<false><<<dim3(mt, 4), blk, 0, stream>>>(qb, vwt, value_b, valueb, M_, 256, 256);
  gemm_kernel<false><<<dim3(mt, 6), blk, 0, stream>>>(qb, oawt, oabias, OA, M_, 256, 384);
  msda_sample<<<dim3(M_ * 2), blk, 0, stream>>>(valueb, OA, refpts, sampled);
  gemm_kernel<false><<<dim3(mt, 4), blk, 0, stream>>>(sampled, outwt, out_b, tmp, M_, 256, 256);
  ln_kernel<float><<<dim3((M_ + 3) / 4), blk, 0, stream>>>(tmp, q, ln1_g, ln1_b, nullptr, x, M_);
  gemm_kernel<true><<<dim3(mt, 16), blk, 0, stream>>>(x, f1wt, ff1_b, hb, M_, 256, 1024);
  gemm_kernel<false><<<dim3(mt, 4), blk, 0, stream>>>(hb, f2wt, ff2_b, tmp, M_, 1024, 256);
  ln_kernel<bf16><<<dim3((M_ + 3) / 4), blk, 0, stream>>>(tmp, x, ln2_g, ln2_b, (float*)d_out, nullptr, M_);
}